// Round 4
// baseline (145.297 us; speedup 1.0000x reference)
//
#include <hip/hip_runtime.h>
#include <hip/hip_bf16.h>
#include <math.h>

// Problem: VOCAB=50257, E=64, D=16, DK=32, B*S=65536, membership p=0.05
#define EDIM 64
#define DDOM 16
#define DKDIM 32
#define NTHREADS 256
#define NBA 1024            // job-A blocks in prep (out = h streaming)
#define KJ 16               // chunk-blocks per domain in mlp

// ws layout: int cnt[16]; then int lists[16][ntok]  (lists hold token POSITIONS)
//
// Domain-major structure. prep writes out=h and compacts per-domain active
// position lists; mlp stages one domain's W1^T/W2 in LDS once (17 KB, reused
// across 256 tokens/block), computes corr per token in registers, and
// atomicAdds 0.1*corr into out via LDS-transposed coalesced row atomics.
// R3 crash fix: mlp must gather tab by TOKEN ID x[pos], not by position.

// ---------------------------------------------------------------------------
__global__ void prep_kernel(const int* __restrict__ x,
                            const float* __restrict__ tab,
                            const unsigned char* __restrict__ memb,
                            float* __restrict__ out,
                            int* __restrict__ cnt,      // [16]
                            int* __restrict__ lists,    // [16][ntok]
                            int ntok)
{
    const int thr = threadIdx.x;
    if (blockIdx.x < NBA) {
        // ---- job A: out = embed_table[x]  (coalesced float4 gather-stream)
        const int nf4 = ntok * 16;
        for (int i = blockIdx.x * NTHREADS + thr; i < nf4; i += NBA * NTHREADS) {
            int t = i >> 4, s = i & 15;
            int tok = x[t];
            float4 hv = ((const float4*)(tab + (size_t)tok * EDIM))[s];
            ((float4*)(out + (size_t)t * EDIM))[s] = hv;
        }
        return;
    }
    // ---- job B: membership dtype detect + per-domain compaction
    __shared__ int det;
    __shared__ int lcnt[DDOM], lbase[DDOM], lpos[DDOM];
    if (thr == 0) det = 0;
    if (thr < DDOM) lcnt[thr] = 0;
    __syncthreads();
    {   // scan first 4096 bytes (membership >= 804112 elements >= 1 B: in-bounds)
        const uint4 v = ((const uint4*)memb)[thr];
        unsigned int w[4] = {v.x, v.y, v.z, v.w};
        int saw = 0;
        #pragma unroll
        for (int dw = 0; dw < 4; ++dw)
            #pragma unroll
            for (int b = 0; b < 4; ++b) {
                unsigned int byte = (w[dw] >> (8 * b)) & 0xFFu;
                if (byte > 1u) saw |= 1;            // bf16 signature bytes
                if (byte == 1u && b != 0) saw |= 2; // '1' at offset %4 != 0 -> u8
            }
        if (saw) atomicOr(&det, saw);
    }
    __syncthreads();
    const int mcode = det;

    const int t = (blockIdx.x - NBA) * NTHREADS + thr;
    unsigned int m = 0;
    if (t < ntok) {
        int tok = x[t];
        if (mcode & 1) {          // bf16 0.0/1.0
            const unsigned short* p = (const unsigned short*)memb + (size_t)tok * DDOM;
            #pragma unroll
            for (int d = 0; d < DDOM; ++d) m |= (unsigned)(p[d] != 0) << d;
        } else if (mcode & 2) {   // uint8
            const unsigned char* p = memb + (size_t)tok * DDOM;
            #pragma unroll
            for (int d = 0; d < DDOM; ++d) m |= (unsigned)(p[d] != 0) << d;
        } else {                  // int32
            const int* p = (const int*)memb + (size_t)tok * DDOM;
            #pragma unroll
            for (int d = 0; d < DDOM; ++d) m |= (unsigned)(p[d] != 0) << d;
        }
    }
    // count per domain in LDS
    #pragma unroll
    for (int d = 0; d < DDOM; ++d)
        if ((m >> d) & 1u) atomicAdd(&lcnt[d], 1);
    __syncthreads();
    if (thr < DDOM) {
        lbase[thr] = atomicAdd(&cnt[thr], lcnt[thr]);  // reserve global range
        lpos[thr] = 0;
    }
    __syncthreads();
    #pragma unroll
    for (int d = 0; d < DDOM; ++d)
        if ((m >> d) & 1u) {
            int p = atomicAdd(&lpos[d], 1);
            lists[(size_t)d * ntok + lbase[d] + p] = t;   // position, not id
        }
}

// ---------------------------------------------------------------------------
// mlp: grid = 16 domains x KJ chunk-blocks, 256 threads, 1 token/thread.
// Weights LDS-resident per block; broadcast ds_read_b128 (uniform addr,
// conflict-free); 4 rotating partial accumulators break the FMA dep chain.
// ---------------------------------------------------------------------------
__global__ void mlp_kernel(const int* __restrict__ lists,
                           const int* __restrict__ cnt,
                           const int* __restrict__ x,
                           const float* __restrict__ tab,
                           const float* __restrict__ W1,   // [D][E][DK]
                           const float* __restrict__ W2,   // [D][DK][E]
                           float* __restrict__ out,
                           int ntok)
{
    __shared__ float w1t[DKDIM][68];     // W1[d]^T: [k][e], row-pad to 68
    __shared__ float w2s[DKDIM][68];     // W2[d]:  [k][e]
    __shared__ float cbuf[4][32][68];    // per-wave corr transpose staging

    const int thr = threadIdx.x, lane = thr & 63, wid = thr >> 6;
    const int d = blockIdx.x >> 4;
    const int j = blockIdx.x & (KJ - 1);
    const int n = cnt[d];
    if (j * NTHREADS >= n) return;       // uniform early-exit

    // stage weights once per block
    const float* __restrict__ w1g = W1 + d * (EDIM * DKDIM);
    for (int i = thr; i < EDIM * DKDIM; i += NTHREADS) {
        int e = i >> 5, k = i & 31;      // w1g[e*32+k], coalesced read
        w1t[k][e] = w1g[i];
    }
    const float* __restrict__ w2g = W2 + d * (DKDIM * EDIM);
    for (int i = thr; i < DKDIM * EDIM; i += NTHREADS) {
        int k = i >> 6, e = i & 63;
        w2s[k][e] = w2g[i];
    }
    __syncthreads();

    for (int base = j * NTHREADS; base < n; base += KJ * NTHREADS) {
        const int ti = base + thr;
        const bool valid = ti < n;
        const int tk    = valid ? lists[(size_t)d * ntok + ti] : 0;  // position
        const int tokid = valid ? x[tk] : 0;                          // token id

        // h row into registers (16x float4, one latency exposure)
        float4 h[16];
        const float4* __restrict__ hrow = (const float4*)(tab + (size_t)tokid * EDIM);
        #pragma unroll
        for (int i = 0; i < 16; ++i) h[i] = hrow[i];

        // step1: g[k] = gelu( sum_e h[e] * W1t[k][e] )
        float g[DKDIM];
        #pragma unroll
        for (int k = 0; k < DKDIM; ++k) {
            const float4* __restrict__ wrow = (const float4*)&w1t[k][0];
            float u0 = 0.f, u1 = 0.f, u2 = 0.f, u3 = 0.f;
            #pragma unroll
            for (int gi = 0; gi < 16; gi += 4) {
                float4 wa = wrow[gi + 0];
                u0 = fmaf(h[gi + 0].x, wa.x, u0); u0 = fmaf(h[gi + 0].y, wa.y, u0);
                u0 = fmaf(h[gi + 0].z, wa.z, u0); u0 = fmaf(h[gi + 0].w, wa.w, u0);
                float4 wb = wrow[gi + 1];
                u1 = fmaf(h[gi + 1].x, wb.x, u1); u1 = fmaf(h[gi + 1].y, wb.y, u1);
                u1 = fmaf(h[gi + 1].z, wb.z, u1); u1 = fmaf(h[gi + 1].w, wb.w, u1);
                float4 wc = wrow[gi + 2];
                u2 = fmaf(h[gi + 2].x, wc.x, u2); u2 = fmaf(h[gi + 2].y, wc.y, u2);
                u2 = fmaf(h[gi + 2].z, wc.z, u2); u2 = fmaf(h[gi + 2].w, wc.w, u2);
                float4 wd = wrow[gi + 3];
                u3 = fmaf(h[gi + 3].x, wd.x, u3); u3 = fmaf(h[gi + 3].y, wd.y, u3);
                u3 = fmaf(h[gi + 3].z, wd.z, u3); u3 = fmaf(h[gi + 3].w, wd.w, u3);
            }
            float u = (u0 + u1) + (u2 + u3);
            // exact GELU: u*Phi(u); |u|~N(0,0.0016) -> odd Taylor, erff fallback
            float au = fabsf(u), gg;
            if (__builtin_expect(au > 0.35f, 0)) {
                gg = 0.5f * u * (1.f + erff(u * 0.70710678118654752f));
            } else {
                float uu = u * u;
                gg = u * (0.5f + u * (0.3989422804f + uu * (-0.06649038f + uu * 0.00997356f)));
            }
            g[k] = gg;
        }

        // step2: corr[e] = sum_k g[k] * W2[k][e]  (h registers now dead)
        float4 c[16];
        #pragma unroll
        for (int gi = 0; gi < 16; ++gi) {
            float4 acc = {0.f, 0.f, 0.f, 0.f};
            #pragma unroll
            for (int k = 0; k < DKDIM; ++k) {
                float4 w = ((const float4*)&w2s[k][0])[gi];
                acc.x = fmaf(g[k], w.x, acc.x);
                acc.y = fmaf(g[k], w.y, acc.y);
                acc.z = fmaf(g[k], w.z, acc.z);
                acc.w = fmaf(g[k], w.w, acc.w);
            }
            c[gi] = acc;
        }

        // epilogue: transpose via LDS (two 32-token halves), coalesced row atomics
        #pragma unroll
        for (int h2 = 0; h2 < 2; ++h2) {
            if ((lane >> 5) == h2) {
                int r = lane & 31;
                #pragma unroll
                for (int gi = 0; gi < 16; ++gi)
                    *((float4*)&cbuf[wid][r][gi * 4]) = c[gi];
            }
            for (int r = 0; r < 32; ++r) {
                int src = h2 * 32 + r;
                int ti_r = base + wid * 64 + src;   // wave-uniform
                if (ti_r < n) {
                    int tks = __shfl(tk, src, 64);  // token POSITION of lane src
                    atomicAdd(&out[(size_t)tks * EDIM + lane], 0.1f * cbuf[wid][r][lane]);
                }
            }
        }
    }
}

// ---------------------------------------------------------------------------
// Fallback (ws too small for lists): round-2 fused kernel, known-correct.
// ---------------------------------------------------------------------------
__global__ __launch_bounds__(256, 4) void domain_embed_fused(
    const int* __restrict__ x, const float* __restrict__ tab,
    const float* __restrict__ W1, const float* __restrict__ W2,
    const unsigned char* __restrict__ memb, float* __restrict__ out, int ntok)
{
    __shared__ float h_lds[32][EDIM];
    __shared__ float corr[32][EDIM];
    __shared__ int   tok_lds[32];
    __shared__ unsigned int mask_lds[32];
    __shared__ unsigned short pairs[32 * DDOM];
    __shared__ int npairs;
    __shared__ int det_wave[4];
    const int thr = threadIdx.x, lane = thr & 63, wid = thr >> 6;
    const int tok0 = blockIdx.x * 32;
    if (thr < 32) { int t = tok0 + thr; tok_lds[thr] = (t < ntok) ? x[t] : 0; }
    #pragma unroll
    for (int i = 0; i < 8; ++i) ((float*)corr)[thr + i * 256] = 0.f;
    if (thr == 0) npairs = 0;
    {
        const uint4 v = ((const uint4*)memb)[thr];
        unsigned int w[4] = {v.x, v.y, v.z, v.w};
        bool sawbf = false, saw8 = false;
        #pragma unroll
        for (int dw = 0; dw < 4; ++dw)
            #pragma unroll
            for (int b = 0; b < 4; ++b) {
                unsigned int byte = (w[dw] >> (8 * b)) & 0xFFu;
                if (byte > 1u) sawbf = true;
                if (byte == 1u && b != 0) saw8 = true;
            }
        unsigned long long b1 = __ballot(sawbf), b2 = __ballot(saw8);
        if (lane == 0) det_wave[wid] = (b1 ? 1 : 0) | (b2 ? 2 : 0);
    }
    __syncthreads();
    const int mcode = det_wave[0] | det_wave[1] | det_wave[2] | det_wave[3];
    #pragma unroll
    for (int pass = 0; pass < 2; ++pass) {
        int row = pass * 16 + (thr >> 4);
        const float4 hv = ((const float4*)(tab + (size_t)tok_lds[row] * EDIM))[thr & 15];
        ((float4*)&h_lds[row][0])[thr & 15] = hv;
    }
    if (thr < 32) {
        int tokid = tok_lds[thr];
        unsigned int m = 0;
        if (mcode & 1) { const unsigned short* p = (const unsigned short*)memb + (size_t)tokid * DDOM;
            #pragma unroll
            for (int d = 0; d < DDOM; ++d) m |= (unsigned)(p[d] != 0) << d;
        } else if (mcode & 2) { const unsigned char* p = memb + (size_t)tokid * DDOM;
            #pragma unroll
            for (int d = 0; d < DDOM; ++d) m |= (unsigned)(p[d] != 0) << d;
        } else { const int* p = (const int*)memb + (size_t)tokid * DDOM;
            #pragma unroll
            for (int d = 0; d < DDOM; ++d) m |= (unsigned)(p[d] != 0) << d;
        }
        mask_lds[thr] = m;
    }
    __syncthreads();
    for (int cc = thr; cc < 32 * DDOM; cc += 256) {
        int t = cc >> 4, d = cc & 15;
        if ((mask_lds[t] >> d) & 1u) { int idx = atomicAdd(&npairs, 1); pairs[idx] = (unsigned short)cc; }
    }
    __syncthreads();
    const int np = npairs, k = lane & 31, p = lane >> 5;
    for (int pi = wid; pi < np; pi += 4) {
        int cc = pairs[pi], t = cc >> 4, d = cc & 15;
        const float* __restrict__ w1 = W1 + d * (EDIM * DKDIM);
        float u = 0.f;
        #pragma unroll
        for (int j4 = 0; j4 < 8; ++j4) {
            float4 hv = ((const float4*)&h_lds[t][p * 32])[j4];
            int e = p * 32 + j4 * 4;
            u = fmaf(hv.x, w1[(e + 0) * DKDIM + k], u);
            u = fmaf(hv.y, w1[(e + 1) * DKDIM + k], u);
            u = fmaf(hv.z, w1[(e + 2) * DKDIM + k], u);
            u = fmaf(hv.w, w1[(e + 3) * DKDIM + k], u);
        }
        u += __shfl_xor(u, 32, 64);
        float gg, au = fabsf(u);
        if (__builtin_expect(__ballot(au > 0.35f) != 0ull, 0))
            gg = 0.5f * u * (1.f + erff(u * 0.70710678118654752f));
        else { float uu = u * u; gg = u * (0.5f + u * (0.3989422804f + uu * (-0.06649038f + uu * 0.00997356f))); }
        const float* __restrict__ w2 = W2 + d * (DKDIM * EDIM);
        float cp = 0.f;
        #pragma unroll
        for (int kk = 0; kk < DKDIM; ++kk) cp = fmaf(__shfl(gg, kk, 64), w2[kk * EDIM + lane], cp);
        atomicAdd(&corr[t][lane], cp);
    }
    __syncthreads();
    #pragma unroll
    for (int pass = 0; pass < 2; ++pass) {
        int row = pass * 16 + (thr >> 4), gt = tok0 + row;
        if (gt < ntok) {
            float4 hv = ((const float4*)&h_lds[row][0])[thr & 15];
            float4 cv = ((const float4*)&corr[row][0])[thr & 15];
            float4 o = {hv.x + 0.1f * cv.x, hv.y + 0.1f * cv.y, hv.z + 0.1f * cv.z, hv.w + 0.1f * cv.w};
            ((float4*)(out + (size_t)gt * EDIM))[thr & 15] = o;
        }
    }
}

extern "C" void kernel_launch(void* const* d_in, const int* in_sizes, int n_in,
                              void* d_out, int out_size, void* d_ws, size_t ws_size,
                              hipStream_t stream) {
    const int*   x    = (const int*)  d_in[0];
    const float* tab  = (const float*)d_in[1];
    const float* W1   = (const float*)d_in[2];
    const float* W2   = (const float*)d_in[3];
    const unsigned char* memb = (const unsigned char*)d_in[4];
    float* out = (float*)d_out;
    const int ntok = in_sizes[0];

    const size_t need = 64 + (size_t)DDOM * (size_t)ntok * sizeof(int);
    if (ws_size >= need) {
        int* cnt   = (int*)d_ws;
        int* lists = (int*)d_ws + 16;
        hipMemsetAsync(d_ws, 0, 64, stream);               // zero cnt (ws poisoned 0xAA)
        const int nbb = (ntok + NTHREADS - 1) / NTHREADS;
        prep_kernel<<<NBA + nbb, NTHREADS, 0, stream>>>(x, tab, memb, out, cnt, lists, ntok);
        mlp_kernel<<<DDOM * KJ, NTHREADS, 0, stream>>>(lists, cnt, x, tab, W1, W2, out, ntok);
    } else {
        const int blocks = (ntok + 31) / 32;
        domain_embed_fused<<<blocks, NTHREADS, 0, stream>>>(x, tab, W1, W2, memb, out, ntok);
    }
}

// Round 5
// 118.522 us; speedup vs baseline: 1.2259x; 1.2259x over previous
//
#include <hip/hip_runtime.h>
#include <hip/hip_bf16.h>
#include <math.h>

// Problem: VOCAB=50257, E=64, D=16, DK=32, B*S=65536, membership p=0.05
#define EDIM 64
#define DDOM 16
#define DKDIM 32
#define NTHREADS 256
#define NBA 1024            // job-A blocks in prep (out = h streaming)
#define MBD 16              // blocks per domain in mlp2

// ws layout: int cnt[16]; then int lists[16][ntok]  (positions, not ids)
//
// Domain-major. prep: out=h stream + per-domain active-position compaction.
// mlp2: one domain per block, weights fp32 in LDS (32 KB). One wave = 64
// same-domain tokens, lane = token. All weight reads are wave-uniform LDS
// broadcasts; step1+step2 fused per k (no g[] array, no dynamic local
// indexing); epilogue transposes corr via padded LDS and issues coalesced
// row atomics. R4 failure mode (1 wave/SIMD, every latency exposed, 1024
// LDS reads/thread) fixed by fusing loops + uniform broadcast + reg-held c.

// ---------------------------------------------------------------------------
__global__ void prep_kernel(const int* __restrict__ x,
                            const float* __restrict__ tab,
                            const unsigned char* __restrict__ memb,
                            float* __restrict__ out,
                            int* __restrict__ cnt,      // [16]
                            int* __restrict__ lists,    // [16][ntok]
                            int ntok)
{
    const int thr = threadIdx.x;
    if (blockIdx.x < NBA) {
        // ---- job A: out = embed_table[x]  (coalesced float4 gather-stream)
        const int nf4 = ntok * 16;
        for (int i = blockIdx.x * NTHREADS + thr; i < nf4; i += NBA * NTHREADS) {
            int t = i >> 4, s = i & 15;
            int tok = x[t];
            float4 hv = ((const float4*)(tab + (size_t)tok * EDIM))[s];
            ((float4*)(out + (size_t)t * EDIM))[s] = hv;
        }
        return;
    }
    // ---- job B: membership dtype detect + per-domain compaction
    __shared__ int det;
    __shared__ int lcnt[DDOM], lbase[DDOM], lpos[DDOM];
    if (thr == 0) det = 0;
    if (thr < DDOM) lcnt[thr] = 0;
    __syncthreads();
    {   // scan first 4096 bytes (membership >= 804112 elements >= 1 B: in-bounds)
        const uint4 v = ((const uint4*)memb)[thr];
        unsigned int w[4] = {v.x, v.y, v.z, v.w};
        int saw = 0;
        #pragma unroll
        for (int dw = 0; dw < 4; ++dw)
            #pragma unroll
            for (int b = 0; b < 4; ++b) {
                unsigned int byte = (w[dw] >> (8 * b)) & 0xFFu;
                if (byte > 1u) saw |= 1;            // bf16 signature bytes
                if (byte == 1u && b != 0) saw |= 2; // '1' at offset %4 != 0 -> u8
            }
        if (saw) atomicOr(&det, saw);
    }
    __syncthreads();
    const int mcode = det;

    const int t = (blockIdx.x - NBA) * NTHREADS + thr;
    unsigned int m = 0;
    if (t < ntok) {
        int tok = x[t];
        if (mcode & 1) {          // bf16 0.0/1.0
            const unsigned short* p = (const unsigned short*)memb + (size_t)tok * DDOM;
            #pragma unroll
            for (int d = 0; d < DDOM; ++d) m |= (unsigned)(p[d] != 0) << d;
        } else if (mcode & 2) {   // uint8
            const unsigned char* p = memb + (size_t)tok * DDOM;
            #pragma unroll
            for (int d = 0; d < DDOM; ++d) m |= (unsigned)(p[d] != 0) << d;
        } else {                  // int32
            const int* p = (const int*)memb + (size_t)tok * DDOM;
            #pragma unroll
            for (int d = 0; d < DDOM; ++d) m |= (unsigned)(p[d] != 0) << d;
        }
    }
    #pragma unroll
    for (int d = 0; d < DDOM; ++d)
        if ((m >> d) & 1u) atomicAdd(&lcnt[d], 1);
    __syncthreads();
    if (thr < DDOM) {
        lbase[thr] = atomicAdd(&cnt[thr], lcnt[thr]);  // reserve global range
        lpos[thr] = 0;
    }
    __syncthreads();
    #pragma unroll
    for (int d = 0; d < DDOM; ++d)
        if ((m >> d) & 1u) {
            int p = atomicAdd(&lpos[d], 1);
            lists[(size_t)d * ntok + lbase[d] + p] = t;   // position
        }
}

// ---------------------------------------------------------------------------
// mlp2: grid = 16 domains x MBD blocks, 256 threads (4 waves).
// Wave = 64 same-domain tokens, lane = token. Weight reads uniform-broadcast.
// ---------------------------------------------------------------------------
__global__ __launch_bounds__(256, 1) void mlp2_kernel(
    const int* __restrict__ lists,
    const int* __restrict__ cnt,
    const int* __restrict__ x,
    const float* __restrict__ tab,
    const float* __restrict__ W1,   // [D][E][DK]
    const float* __restrict__ W2,   // [D][DK][E]
    float* __restrict__ out,
    int ntok)
{
    __shared__ float w1t[DKDIM][EDIM];   // W1[d]^T: [k][e]  8 KB
    __shared__ float w2s[DKDIM][EDIM];   // W2[d]:  [k][e]  8 KB
    __shared__ float cbuf[4][64][17];    // per-wave transpose, 17-pad  17.4 KB

    const int thr = threadIdx.x, lane = thr & 63, wid = thr >> 6;
    const int d   = blockIdx.x >> 4;     // MBD = 16
    const int blk = blockIdx.x & (MBD - 1);
    const int n   = cnt[d];

    // stage this domain's weights (fp32) once
    const float* __restrict__ w1g = W1 + d * (EDIM * DKDIM);
    for (int i = thr; i < EDIM * DKDIM; i += NTHREADS) {
        int e = i >> 5, k = i & 31;      // w1g is [e][k]
        w1t[k][e] = w1g[i];
    }
    const float* __restrict__ w2g = W2 + d * (DKDIM * EDIM);
    for (int i = thr; i < DKDIM * EDIM; i += NTHREADS) {
        w2s[i >> 6][i & 63] = w2g[i];    // same [k][e] layout
    }
    __syncthreads();

    const int wg = blk * 4 + wid;        // wave index within domain: 0..63
    for (int base = wg * 64; base < n; base += 64 * 64) {
        const int ti = base + lane;
        const bool valid = ti < n;
        const int pos   = valid ? lists[(size_t)d * ntok + ti] : 0;  // position
        const int tokid = valid ? x[pos] : 0;                        // token id

        float h[EDIM];
        {
            const float4* __restrict__ hr = (const float4*)(tab + (size_t)tokid * EDIM);
            #pragma unroll
            for (int i = 0; i < 16; ++i) ((float4*)h)[i] = hr[i];
        }

        float c[EDIM];
        #pragma unroll
        for (int e = 0; e < EDIM; ++e) c[e] = 0.f;

        // fused step1+step2 per k: u_k -> gelu -> rank-1 update of c
        #pragma unroll 2
        for (int k = 0; k < DKDIM; ++k) {
            const float4* __restrict__ wr = (const float4*)&w1t[k][0];  // uniform
            float u0 = 0.f, u1 = 0.f, u2 = 0.f, u3 = 0.f;
            #pragma unroll
            for (int q = 0; q < 16; q += 4) {
                float4 a = wr[q + 0];
                u0 = fmaf(h[4*q+ 0], a.x, u0); u0 = fmaf(h[4*q+ 1], a.y, u0);
                u0 = fmaf(h[4*q+ 2], a.z, u0); u0 = fmaf(h[4*q+ 3], a.w, u0);
                float4 b = wr[q + 1];
                u1 = fmaf(h[4*q+ 4], b.x, u1); u1 = fmaf(h[4*q+ 5], b.y, u1);
                u1 = fmaf(h[4*q+ 6], b.z, u1); u1 = fmaf(h[4*q+ 7], b.w, u1);
                float4 e2 = wr[q + 2];
                u2 = fmaf(h[4*q+ 8], e2.x, u2); u2 = fmaf(h[4*q+ 9], e2.y, u2);
                u2 = fmaf(h[4*q+10], e2.z, u2); u2 = fmaf(h[4*q+11], e2.w, u2);
                float4 f2 = wr[q + 3];
                u3 = fmaf(h[4*q+12], f2.x, u3); u3 = fmaf(h[4*q+13], f2.y, u3);
                u3 = fmaf(h[4*q+14], f2.z, u3); u3 = fmaf(h[4*q+15], f2.w, u3);
            }
            float u = (u0 + u1) + (u2 + u3);
            // exact GELU u*Phi(u): odd Taylor (|u|~1.6e-3), guarded erff fallback
            float gg, au = fabsf(u);
            if (__builtin_expect(au > 0.35f, 0)) {
                gg = 0.5f * u * (1.f + erff(u * 0.70710678118654752f));
            } else {
                float uu = u * u;
                gg = u * (0.5f + u * (0.3989422804f + uu * (-0.06649038f + uu * 0.00997356f)));
            }
            const float4* __restrict__ w2r = (const float4*)&w2s[k][0];  // uniform
            #pragma unroll
            for (int q = 0; q < 16; ++q) {
                float4 w = w2r[q];
                c[4*q+0] = fmaf(gg, w.x, c[4*q+0]);
                c[4*q+1] = fmaf(gg, w.y, c[4*q+1]);
                c[4*q+2] = fmaf(gg, w.z, c[4*q+2]);
                c[4*q+3] = fmaf(gg, w.w, c[4*q+3]);
            }
        }

        // epilogue: per-wave LDS transpose (4 e-chunks of 16) + coalesced atomics
        const int r0 = lane >> 4;       // 0..3 token rows per atomic instr
        const int ee = lane & 15;       // e within chunk
        #pragma unroll
        for (int ec = 0; ec < 4; ++ec) {
            #pragma unroll
            for (int e = 0; e < 16; ++e)
                cbuf[wid][lane][e] = c[ec * 16 + e];   // same-wave RAW, in-order DS pipe
            for (int rr = 0; rr < 64; rr += 4) {
                int tloc = rr + r0;
                int p2 = __shfl(pos, tloc, 64);        // all lanes active here
                if (base + tloc < n) {
                    atomicAdd(&out[(size_t)p2 * EDIM + ec * 16 + ee],
                              0.1f * cbuf[wid][tloc][ee]);
                }
            }
        }
    }
}

// ---------------------------------------------------------------------------
// Fallback (ws too small for lists): round-2 fused kernel, known-correct.
// ---------------------------------------------------------------------------
__global__ __launch_bounds__(256, 4) void domain_embed_fused(
    const int* __restrict__ x, const float* __restrict__ tab,
    const float* __restrict__ W1, const float* __restrict__ W2,
    const unsigned char* __restrict__ memb, float* __restrict__ out, int ntok)
{
    __shared__ float h_lds[32][EDIM];
    __shared__ float corr[32][EDIM];
    __shared__ int   tok_lds[32];
    __shared__ unsigned int mask_lds[32];
    __shared__ unsigned short pairs[32 * DDOM];
    __shared__ int npairs;
    __shared__ int det_wave[4];
    const int thr = threadIdx.x, lane = thr & 63, wid = thr >> 6;
    const int tok0 = blockIdx.x * 32;
    if (thr < 32) { int t = tok0 + thr; tok_lds[thr] = (t < ntok) ? x[t] : 0; }
    #pragma unroll
    for (int i = 0; i < 8; ++i) ((float*)corr)[thr + i * 256] = 0.f;
    if (thr == 0) npairs = 0;
    {
        const uint4 v = ((const uint4*)memb)[thr];
        unsigned int w[4] = {v.x, v.y, v.z, v.w};
        bool sawbf = false, saw8 = false;
        #pragma unroll
        for (int dw = 0; dw < 4; ++dw)
            #pragma unroll
            for (int b = 0; b < 4; ++b) {
                unsigned int byte = (w[dw] >> (8 * b)) & 0xFFu;
                if (byte > 1u) sawbf = true;
                if (byte == 1u && b != 0) saw8 = true;
            }
        unsigned long long b1 = __ballot(sawbf), b2 = __ballot(saw8);
        if (lane == 0) det_wave[wid] = (b1 ? 1 : 0) | (b2 ? 2 : 0);
    }
    __syncthreads();
    const int mcode = det_wave[0] | det_wave[1] | det_wave[2] | det_wave[3];
    #pragma unroll
    for (int pass = 0; pass < 2; ++pass) {
        int row = pass * 16 + (thr >> 4);
        const float4 hv = ((const float4*)(tab + (size_t)tok_lds[row] * EDIM))[thr & 15];
        ((float4*)&h_lds[row][0])[thr & 15] = hv;
    }
    if (thr < 32) {
        int tokid = tok_lds[thr];
        unsigned int m = 0;
        if (mcode & 1) { const unsigned short* p = (const unsigned short*)memb + (size_t)tokid * DDOM;
            #pragma unroll
            for (int d = 0; d < DDOM; ++d) m |= (unsigned)(p[d] != 0) << d;
        } else if (mcode & 2) { const unsigned char* p = memb + (size_t)tokid * DDOM;
            #pragma unroll
            for (int d = 0; d < DDOM; ++d) m |= (unsigned)(p[d] != 0) << d;
        } else { const int* p = (const int*)memb + (size_t)tokid * DDOM;
            #pragma unroll
            for (int d = 0; d < DDOM; ++d) m |= (unsigned)(p[d] != 0) << d;
        }
        mask_lds[thr] = m;
    }
    __syncthreads();
    for (int cc = thr; cc < 32 * DDOM; cc += 256) {
        int t = cc >> 4, d = cc & 15;
        if ((mask_lds[t] >> d) & 1u) { int idx = atomicAdd(&npairs, 1); pairs[idx] = (unsigned short)cc; }
    }
    __syncthreads();
    const int np = npairs, k = lane & 31, p = lane >> 5;
    for (int pi = wid; pi < np; pi += 4) {
        int cc = pairs[pi], t = cc >> 4, d = cc & 15;
        const float* __restrict__ w1 = W1 + d * (EDIM * DKDIM);
        float u = 0.f;
        #pragma unroll
        for (int j4 = 0; j4 < 8; ++j4) {
            float4 hv = ((const float4*)&h_lds[t][p * 32])[j4];
            int e = p * 32 + j4 * 4;
            u = fmaf(hv.x, w1[(e + 0) * DKDIM + k], u);
            u = fmaf(hv.y, w1[(e + 1) * DKDIM + k], u);
            u = fmaf(hv.z, w1[(e + 2) * DKDIM + k], u);
            u = fmaf(hv.w, w1[(e + 3) * DKDIM + k], u);
        }
        u += __shfl_xor(u, 32, 64);
        float gg, au = fabsf(u);
        if (__builtin_expect(__ballot(au > 0.35f) != 0ull, 0))
            gg = 0.5f * u * (1.f + erff(u * 0.70710678118654752f));
        else { float uu = u * u; gg = u * (0.5f + u * (0.3989422804f + uu * (-0.06649038f + uu * 0.00997356f))); }
        const float* __restrict__ w2 = W2 + d * (DKDIM * EDIM);
        float cp = 0.f;
        #pragma unroll
        for (int kk = 0; kk < DKDIM; ++kk) cp = fmaf(__shfl(gg, kk, 64), w2[kk * EDIM + lane], cp);
        atomicAdd(&corr[t][lane], cp);
    }
    __syncthreads();
    #pragma unroll
    for (int pass = 0; pass < 2; ++pass) {
        int row = pass * 16 + (thr >> 4), gt = tok0 + row;
        if (gt < ntok) {
            float4 hv = ((const float4*)&h_lds[row][0])[thr & 15];
            float4 cv = ((const float4*)&corr[row][0])[thr & 15];
            float4 o = {hv.x + 0.1f * cv.x, hv.y + 0.1f * cv.y, hv.z + 0.1f * cv.z, hv.w + 0.1f * cv.w};
            ((float4*)(out + (size_t)gt * EDIM))[thr & 15] = o;
        }
    }
}

extern "C" void kernel_launch(void* const* d_in, const int* in_sizes, int n_in,
                              void* d_out, int out_size, void* d_ws, size_t ws_size,
                              hipStream_t stream) {
    const int*   x    = (const int*)  d_in[0];
    const float* tab  = (const float*)d_in[1];
    const float* W1   = (const float*)d_in[2];
    const float* W2   = (const float*)d_in[3];
    const unsigned char* memb = (const unsigned char*)d_in[4];
    float* out = (float*)d_out;
    const int ntok = in_sizes[0];

    const size_t need = 64 + (size_t)DDOM * (size_t)ntok * sizeof(int);
    if (ws_size >= need) {
        int* cnt   = (int*)d_ws;
        int* lists = (int*)d_ws + 16;
        hipMemsetAsync(d_ws, 0, 64, stream);               // zero cnt (ws poisoned 0xAA)
        const int nbb = (ntok + NTHREADS - 1) / NTHREADS;
        prep_kernel<<<NBA + nbb, NTHREADS, 0, stream>>>(x, tab, memb, out, cnt, lists, ntok);
        mlp2_kernel<<<DDOM * MBD, NTHREADS, 0, stream>>>(lists, cnt, x, tab, W1, W2, out, ntok);
    } else {
        const int blocks = (ntok + 31) / 32;
        domain_embed_fused<<<blocks, NTHREADS, 0, stream>>>(x, tab, W1, W2, memb, out, ntok);
    }
}